// Round 17
// baseline (357.449 us; speedup 1.0000x reference)
//
#include <hip/hip_runtime.h>
#include <cstdint>
#include <cstddef>

#define B_    2048
#define L_    13
#define H_    768
#define NROW  (B_ * L_)          // 26624 flattened hidden rows
#define RTEMP 20.0f              // 1 / 0.05
#define NT    12                 // K tiles: 768 / 64
#define RS    768                // fp8 row stride bytes
#define NTILE 3328               // 16 M-panels x 208 N-panels (128x128 tiles)
#define SC1   0x7F7F7F7F         // E8M0 unit scales (2^0) in every byte

typedef int   i32x4  __attribute__((ext_vector_type(4)));
typedef int   i32x8  __attribute__((ext_vector_type(8)));
typedef float f32x16 __attribute__((ext_vector_type(16)));

// ---- f32 -> OCP e4m3fn, RNE, saturating (no NaN/Inf inputs here) ----------
static __device__ __forceinline__ unsigned int f2e4m3(float f) {
  unsigned int u = __float_as_uint(f);
  unsigned int s = (u >> 24) & 0x80u;
  unsigned int ua = u & 0x7fffffffu;
  if (ua >= 0x43e80000u) return s | 0x7eu;          // >= 464 -> saturate 448
  if (ua < 0x3c800000u) {                           // < 2^-6: subnormal range
    int m = (int)rintf(__uint_as_float(ua) * 512.0f);   // 0..8 (8 -> 0x08 = 2^-6)
    return s | (unsigned int)m;
  }
  unsigned int lsb = (ua >> 20) & 1u;
  unsigned int r = ua + 0x7ffffu + lsb;             // RNE to 3 mantissa bits
  int Ee = (int)((r >> 23) & 0xffu) - 127;          // carry handled naturally
  unsigned int mant = (r >> 20) & 7u;
  return s | (unsigned int)(((Ee + 7) << 3) | mant);
}

__device__ __forceinline__ void llds16(const void* g, void* l) {
  __builtin_amdgcn_global_load_lds(
      (const __attribute__((address_space(1))) void*)g,
      (__attribute__((address_space(3))) void*)l, 16, 0, 0);
}

#define BAR do { asm volatile("" ::: "memory");            \
    __builtin_amdgcn_s_barrier();                          \
    asm volatile("" ::: "memory"); } while (0)

// ---------------------------------------------------------------------------
// Kernel 1: L2-normalize rows (f32 math), quantize to e4m3, LINEAR k layout.
// One wave per row, 4 rows/block. Block 0 zeroes S_all/out.
// ---------------------------------------------------------------------------
__global__ __launch_bounds__(256) void k_normalize(
    const float* __restrict__ cls, const float* __restrict__ hidden,
    unsigned char* __restrict__ cn8, unsigned char* __restrict__ hn8,
    float* __restrict__ S_all, float* __restrict__ out)
{
  if (blockIdx.x == 0) {
#pragma unroll
    for (int i = 0; i < 8; ++i) S_all[threadIdx.x * 8 + i] = 0.0f;
    if (threadIdx.x == 0) *out = 0.0f;
  }

  const int wid = threadIdx.x >> 6, lane = threadIdx.x & 63;
  const int row = blockIdx.x * 4 + wid;
  const float4* src; unsigned char* dst;
  if (row < B_) { src = (const float4*)(cls + (size_t)row * H_);           dst = cn8 + (size_t)row * RS; }
  else          { src = (const float4*)(hidden + (size_t)(row - B_) * H_); dst = hn8 + (size_t)(row - B_) * RS; }

  float4 x0 = src[lane], x1 = src[lane + 64], x2 = src[lane + 128];
  float ss = x0.x*x0.x + x0.y*x0.y + x0.z*x0.z + x0.w*x0.w
           + x1.x*x1.x + x1.y*x1.y + x1.z*x1.z + x1.w*x1.w
           + x2.x*x2.x + x2.y*x2.y + x2.z*x2.z + x2.w*x2.w;
#pragma unroll
  for (int m = 1; m < 64; m <<= 1) ss += __shfl_xor(ss, m);
  const float sc = 1.0f / fmaxf(sqrtf(ss), 1e-8f);

  const int k = lane * 4;
  unsigned int p0 = f2e4m3(x0.x*sc) | (f2e4m3(x0.y*sc) << 8) | (f2e4m3(x0.z*sc) << 16) | (f2e4m3(x0.w*sc) << 24);
  unsigned int p1 = f2e4m3(x1.x*sc) | (f2e4m3(x1.y*sc) << 8) | (f2e4m3(x1.z*sc) << 16) | (f2e4m3(x1.w*sc) << 24);
  unsigned int p2 = f2e4m3(x2.x*sc) | (f2e4m3(x2.y*sc) << 8) | (f2e4m3(x2.z*sc) << 16) | (f2e4m3(x2.w*sc) << 24);
  *(unsigned int*)(dst + k)       = p0;
  *(unsigned int*)(dst + k + 256) = p1;
  *(unsigned int*)(dst + k + 512) = p2;
}

// ---------------------------------------------------------------------------
// Kernel 2: MX-scaled fp8 GEMM (unit scales) — R14 skeleton at 2x MFMA rate.
// 128x128 tile, 4 waves 2x2, wave tile 64x64 as 2x2 of 32x32. BK=64, 12
// steps; per step 4x mfma_scale_f32_32x32x64_f8f6f4 (scale = 2^0 -> exact
// same math as non-scaled fp8). A 2-slot dbuf (stage t+1), B 3-slot ring
// (stage t+2), LDS 40KB -> 4 blocks/CU. Counted vmcnt(2) per step.
// A-frag layout: row=lane&31, k=(lane>>5)*32+[0:32) (2 b128 per frag).
// XOR swizzle: unit v=(r&1)*4+2h+j at physical v^((r>>1)&7) per 128B line
// (same algebra as the R14 0-conflict map; staging map identical).
// D-layout (m74/m101): col=lane&31, row=(reg&3)+8*(reg>>2)+4*(lane>>5).
// ---------------------------------------------------------------------------
__global__ __launch_bounds__(256, 4) void k_gemm(
    const unsigned char* __restrict__ cn8,
    const unsigned char* __restrict__ hn8,
    float* __restrict__ S_all,
    float* __restrict__ alignedD)
{
  __shared__ __align__(16) char lds[40960];   // A: 2x8KB @0; B: 3x8KB @16384

  const int tid  = threadIdx.x;
  const int lane = tid & 63;
  const int wid  = tid >> 6;           // 0..3
  const int wm   = wid >> 1;           // 0..1  (M half: 64 rows)
  const int wn   = wid & 1;            // 0..1  (N half: 64 cols)
  const int rr   = lane & 31;          // row/col within 32-tile
  const int h    = lane >> 5;          // K-half select

  // ---- fragment read offsets (XOR swizzle, R14 algebra) ------------------
  // frag (region line) = base*16-lines + (rr>>1); unit v = (rr&1)*4+2h+j.
  const int keyq = (rr >> 1) & 7;
  int offA[2][2], offB[2][2];
#pragma unroll
  for (int mi = 0; mi < 2; ++mi)
#pragma unroll
    for (int j = 0; j < 2; ++j) {
      const int line = wm * 32 + mi * 16 + (rr >> 1);
      const int v    = (rr & 1) * 4 + 2 * h + j;
      offA[mi][j] = line * 128 + ((v ^ keyq) << 4);
    }
#pragma unroll
  for (int ni = 0; ni < 2; ++ni)
#pragma unroll
    for (int j = 0; j < 2; ++j) {
      const int line = wn * 32 + ni * 16 + (rr >> 1);
      const int v    = (rr & 1) * 4 + 2 * h + j;
      offB[ni][j] = line * 128 + ((v ^ keyq) << 4);
    }

  // ---- staging map (identical to R14: linear LDS dest, inv-swz source) ---
  const int slot_un = (tid & 7) ^ ((tid >> 3) & 7);
  const int srow = 2 * (tid >> 3) + (slot_un >> 2);   // 0..63
  const int scb  = (slot_un & 3) << 4;

  // R12 decode: 3328 = 8 XCD x (26 N x 16 M), M-inner within XCD.
  const int tile = blockIdx.x;
  const int xcd  = tile & 7;
  const int idx  = tile >> 3;
  const int brow = (idx & 15) << 7;
  const int bcol = (xcd * 26 + (idx >> 4)) << 7;

  const char* gA = (const char*)cn8 + (size_t)(brow + srow) * RS + scb;
  const char* gB = (const char*)hn8 + (size_t)(bcol + srow) * RS + scb;
  char* ldst = lds + tid * 16;

#define STAGE_A(sb, t) do {                                       \
    const char* a_ = gA + (t) * 64;                               \
    llds16(a_,           ldst + (sb));                            \
    llds16(a_ + 64 * RS, ldst + (sb) + 4096);                     \
  } while (0)
#define STAGE_B(sb, t) do {                                       \
    const char* b_ = gB + (t) * 64;                               \
    llds16(b_,           ldst + (sb));                            \
    llds16(b_ + 64 * RS, ldst + (sb) + 4096);                     \
  } while (0)

  // prologue: A(0), B(0), B(1) issued; A(0)+B(0) landed at vmcnt(2)
  STAGE_A(0, 0);
  STAGE_B(16384, 0);
  STAGE_B(16384 + 8192, 1);
  asm volatile("s_waitcnt vmcnt(2)" ::: "memory");
  BAR;

  f32x16 acc[2][2] = {};

  for (int t = 0; t < NT; ++t) {
    const char* bA = lds + (t & 1) * 8192;
    const char* bB = lds + 16384 + (t % 3) * 8192;

    i32x8 av[2], bv[2];
#pragma unroll
    for (int mi = 0; mi < 2; ++mi) {
      i32x4 lo = *(const i32x4*)(bA + offA[mi][0]);
      i32x4 hi = *(const i32x4*)(bA + offA[mi][1]);
      av[mi] = __builtin_shufflevector(lo, hi, 0, 1, 2, 3, 4, 5, 6, 7);
    }
#pragma unroll
    for (int ni = 0; ni < 2; ++ni) {
      i32x4 lo = *(const i32x4*)(bB + offB[ni][0]);
      i32x4 hi = *(const i32x4*)(bB + offB[ni][1]);
      bv[ni] = __builtin_shufflevector(lo, hi, 0, 1, 2, 3, 4, 5, 6, 7);
    }

    if (t + 1 < NT) STAGE_A(((t + 1) & 1) * 8192, t + 1);
    if (t + 2 < NT) STAGE_B(16384 + ((t + 2) % 3) * 8192, t + 2);

    __builtin_amdgcn_s_setprio(1);
#pragma unroll
    for (int mi = 0; mi < 2; ++mi)
#pragma unroll
      for (int ni = 0; ni < 2; ++ni)
        acc[mi][ni] = __builtin_amdgcn_mfma_scale_f32_32x32x64_f8f6f4(
            av[mi], bv[ni], acc[mi][ni], 0, 0, 0, SC1, 0, SC1);
    __builtin_amdgcn_s_setprio(0);

    if (t + 2 < NT)      { asm volatile("s_waitcnt vmcnt(2)" ::: "memory"); BAR; }
    else if (t + 1 < NT) { asm volatile("s_waitcnt vmcnt(0)" ::: "memory"); BAR; }
  }
#undef STAGE_A
#undef STAGE_B

  // ---- epilogue: D 32x32 layout: col = rr, row = (j&3)+8*(j>>2)+4*h ------
  const int rowb = brow + wm * 64;
  const int colb = bcol + wn * 64;
#pragma unroll
  for (int mi = 0; mi < 2; ++mi) {
#pragma unroll
    for (int j = 0; j < 16; ++j) {
      const int grow = rowb + mi * 32 + (j & 3) + 8 * (j >> 2) + 4 * h;
      float v = 0.f;
#pragma unroll
      for (int ni = 0; ni < 2; ++ni) {
        const int gcol = colb + ni * 32 + rr;
        const float a = acc[mi][ni][j];
        if ((unsigned)(gcol - grow * 13) < 13u) alignedD[gcol] = a;  // raw dot
        v += ((gcol & 2047) == grow) ? 0.f : __expf(RTEMP * a);     // masked sum
      }
      v += __shfl_xor(v, 1); v += __shfl_xor(v, 2);
      v += __shfl_xor(v, 4); v += __shfl_xor(v, 8); v += __shfl_xor(v, 16);
      if (rr == 0) atomicAdd(&S_all[grow], v);    // lanes 0 (h=0) and 32 (h=1)
    }
  }
}

// ---------------------------------------------------------------------------
// Kernel 3: per row i: loss_i = sum_l [ log(exp(20 d_l) + s_i) - 20 d_l ].
// ---------------------------------------------------------------------------
__global__ __launch_bounds__(256) void k_finalize(
    const float* __restrict__ S_all, const float* __restrict__ alignedD,
    float* __restrict__ out)
{
  const int i = blockIdx.x * 256 + threadIdx.x;
  const int lane = threadIdx.x & 63, wid = threadIdx.x >> 6;
  const float s = S_all[i];
  float accv = 0.f;
#pragma unroll
  for (int l = 0; l < L_; l++) {
    const float d = RTEMP * alignedD[i * L_ + l];
    accv += logf(__expf(d) + s) - d;
  }
#pragma unroll
  for (int m = 1; m < 64; m <<= 1) accv += __shfl_xor(accv, m);
  __shared__ float wsum[4];
  if (lane == 0) wsum[wid] = accv;
  __syncthreads();
  if (threadIdx.x == 0)
    atomicAdd(out, (wsum[0] + wsum[1] + wsum[2] + wsum[3]) * (1.0f / (float)(B_ * L_)));
}

// ---------------------------------------------------------------------------
extern "C" void kernel_launch(void* const* d_in, const int* in_sizes, int n_in,
                              void* d_out, int out_size, void* d_ws, size_t ws_size,
                              hipStream_t stream) {
  const float* cls    = (const float*)d_in[0];
  const float* hidden = (const float*)d_in[1];
  float* out = (float*)d_out;

  // ws: hn8 (20,447,232) | cn8 (1,572,864) | S_all (8,192) | alignedD (106,496)
  char* ws = (char*)d_ws;
  unsigned char* hn8 = (unsigned char*)ws;
  unsigned char* cn8 = (unsigned char*)(ws + (size_t)NROW * RS);
  float* S_all    = (float*)(ws + (size_t)NROW * RS + (size_t)B_ * RS);
  float* alignedD = (float*)(ws + (size_t)NROW * RS + (size_t)B_ * RS + B_ * sizeof(float));

  k_normalize<<<(B_ + NROW) / 4, 256, 0, stream>>>(cls, hidden, cn8, hn8, S_all, out);
  k_gemm<<<NTILE, 256, 0, stream>>>(cn8, hn8, S_all, alignedD);
  k_finalize<<<B_ / 256, 256, 0, stream>>>(S_all, alignedD, out);
}

// Round 18
// 246.429 us; speedup vs baseline: 1.4505x; 1.4505x over previous
//
#include <hip/hip_runtime.h>
#include <cstdint>
#include <cstddef>

#define B_    2048
#define L_    13
#define H_    768
#define NROW  (B_ * L_)          // 26624 flattened hidden rows
#define RTEMP 20.0f              // 1 / 0.05
#define NT    12                 // K tiles: 768 / 64
#define RS    768                // fp8 row stride bytes
#define NTILE 3328               // 16 M-panels x 208 N-panels (128x128 tiles)
#define SC1   0x7F7F7F7F         // E8M0 unit scales (2^0) in every byte

typedef int   i32x4  __attribute__((ext_vector_type(4)));
typedef int   i32x8  __attribute__((ext_vector_type(8)));
typedef float f32x16 __attribute__((ext_vector_type(16)));

// ---- f32 -> OCP e4m3fn, RNE, saturating (no NaN/Inf inputs here) ----------
static __device__ __forceinline__ unsigned int f2e4m3(float f) {
  unsigned int u = __float_as_uint(f);
  unsigned int s = (u >> 24) & 0x80u;
  unsigned int ua = u & 0x7fffffffu;
  if (ua >= 0x43e80000u) return s | 0x7eu;          // >= 464 -> saturate 448
  if (ua < 0x3c800000u) {                           // < 2^-6: subnormal range
    int m = (int)rintf(__uint_as_float(ua) * 512.0f);   // 0..8 (8 -> 0x08 = 2^-6)
    return s | (unsigned int)m;
  }
  unsigned int lsb = (ua >> 20) & 1u;
  unsigned int r = ua + 0x7ffffu + lsb;             // RNE to 3 mantissa bits
  int Ee = (int)((r >> 23) & 0xffu) - 127;          // carry handled naturally
  unsigned int mant = (r >> 20) & 7u;
  return s | (unsigned int)(((Ee + 7) << 3) | mant);
}

__device__ __forceinline__ void llds16(const void* g, void* l) {
  __builtin_amdgcn_global_load_lds(
      (const __attribute__((address_space(1))) void*)g,
      (__attribute__((address_space(3))) void*)l, 16, 0, 0);
}

#define BAR do { asm volatile("" ::: "memory");            \
    __builtin_amdgcn_s_barrier();                          \
    asm volatile("" ::: "memory"); } while (0)

// ---------------------------------------------------------------------------
// Kernel 1: L2-normalize rows (f32 math), quantize to e4m3, LINEAR k layout.
// One wave per row, 4 rows/block. Block 0 zeroes S_all/out.
// ---------------------------------------------------------------------------
__global__ __launch_bounds__(256) void k_normalize(
    const float* __restrict__ cls, const float* __restrict__ hidden,
    unsigned char* __restrict__ cn8, unsigned char* __restrict__ hn8,
    float* __restrict__ S_all, float* __restrict__ out)
{
  if (blockIdx.x == 0) {
#pragma unroll
    for (int i = 0; i < 8; ++i) S_all[threadIdx.x * 8 + i] = 0.0f;
    if (threadIdx.x == 0) *out = 0.0f;
  }

  const int wid = threadIdx.x >> 6, lane = threadIdx.x & 63;
  const int row = blockIdx.x * 4 + wid;
  const float4* src; unsigned char* dst;
  if (row < B_) { src = (const float4*)(cls + (size_t)row * H_);           dst = cn8 + (size_t)row * RS; }
  else          { src = (const float4*)(hidden + (size_t)(row - B_) * H_); dst = hn8 + (size_t)(row - B_) * RS; }

  float4 x0 = src[lane], x1 = src[lane + 64], x2 = src[lane + 128];
  float ss = x0.x*x0.x + x0.y*x0.y + x0.z*x0.z + x0.w*x0.w
           + x1.x*x1.x + x1.y*x1.y + x1.z*x1.z + x1.w*x1.w
           + x2.x*x2.x + x2.y*x2.y + x2.z*x2.z + x2.w*x2.w;
#pragma unroll
  for (int m = 1; m < 64; m <<= 1) ss += __shfl_xor(ss, m);
  const float sc = 1.0f / fmaxf(sqrtf(ss), 1e-8f);

  const int k = lane * 4;
  unsigned int p0 = f2e4m3(x0.x*sc) | (f2e4m3(x0.y*sc) << 8) | (f2e4m3(x0.z*sc) << 16) | (f2e4m3(x0.w*sc) << 24);
  unsigned int p1 = f2e4m3(x1.x*sc) | (f2e4m3(x1.y*sc) << 8) | (f2e4m3(x1.z*sc) << 16) | (f2e4m3(x1.w*sc) << 24);
  unsigned int p2 = f2e4m3(x2.x*sc) | (f2e4m3(x2.y*sc) << 8) | (f2e4m3(x2.z*sc) << 16) | (f2e4m3(x2.w*sc) << 24);
  *(unsigned int*)(dst + k)       = p0;
  *(unsigned int*)(dst + k + 256) = p1;
  *(unsigned int*)(dst + k + 512) = p2;
}

// ---------------------------------------------------------------------------
// Kernel 2: MX-scaled fp8 GEMM (unit scales) — R17 with the register budget
// fixed: __launch_bounds__(256, 3) -> 170-reg cap. R17's (256,4)=128 cap
// spilled the f32x16 accumulator to scratch (WRITE_SIZE 759MB). Occupancy
// 3 blocks/CU (LDS 3x40KB=120KB). Everything else identical to R17:
// 128x128 tile, 4 waves 2x2, wave tile 64x64 as 2x2 of 32x32, BK=64,
// 12 steps, 4x mfma_scale_f32_32x32x64_f8f6f4 per step (2x fp8 rate,
// exact math at unit scale), A 2-slot dbuf / B 3-slot ring, vmcnt(2)/step,
// R12 decode, XOR swizzle (verified: absmax=0 in R17), m74/m101 D-layout.
// ---------------------------------------------------------------------------
__global__ __launch_bounds__(256, 3) void k_gemm(
    const unsigned char* __restrict__ cn8,
    const unsigned char* __restrict__ hn8,
    float* __restrict__ S_all,
    float* __restrict__ alignedD)
{
  __shared__ __align__(16) char lds[40960];   // A: 2x8KB @0; B: 3x8KB @16384

  const int tid  = threadIdx.x;
  const int lane = tid & 63;
  const int wid  = tid >> 6;           // 0..3
  const int wm   = wid >> 1;           // 0..1  (M half: 64 rows)
  const int wn   = wid & 1;            // 0..1  (N half: 64 cols)
  const int rr   = lane & 31;          // row/col within 32-tile
  const int h    = lane >> 5;          // K-half select

  // ---- fragment read offsets (XOR swizzle, R14 algebra; R17-verified) ----
  const int keyq = (rr >> 1) & 7;
  int offA[2][2], offB[2][2];
#pragma unroll
  for (int mi = 0; mi < 2; ++mi)
#pragma unroll
    for (int j = 0; j < 2; ++j) {
      const int line = wm * 32 + mi * 16 + (rr >> 1);
      const int v    = (rr & 1) * 4 + 2 * h + j;
      offA[mi][j] = line * 128 + ((v ^ keyq) << 4);
    }
#pragma unroll
  for (int ni = 0; ni < 2; ++ni)
#pragma unroll
    for (int j = 0; j < 2; ++j) {
      const int line = wn * 32 + ni * 16 + (rr >> 1);
      const int v    = (rr & 1) * 4 + 2 * h + j;
      offB[ni][j] = line * 128 + ((v ^ keyq) << 4);
    }

  // ---- staging map (identical to R14: linear LDS dest, inv-swz source) ---
  const int slot_un = (tid & 7) ^ ((tid >> 3) & 7);
  const int srow = 2 * (tid >> 3) + (slot_un >> 2);   // 0..63
  const int scb  = (slot_un & 3) << 4;

  // R12 decode: 3328 = 8 XCD x (26 N x 16 M), M-inner within XCD.
  const int tile = blockIdx.x;
  const int xcd  = tile & 7;
  const int idx  = tile >> 3;
  const int brow = (idx & 15) << 7;
  const int bcol = (xcd * 26 + (idx >> 4)) << 7;

  const char* gA = (const char*)cn8 + (size_t)(brow + srow) * RS + scb;
  const char* gB = (const char*)hn8 + (size_t)(bcol + srow) * RS + scb;
  char* ldst = lds + tid * 16;

#define STAGE_A(sb, t) do {                                       \
    const char* a_ = gA + (t) * 64;                               \
    llds16(a_,           ldst + (sb));                            \
    llds16(a_ + 64 * RS, ldst + (sb) + 4096);                     \
  } while (0)
#define STAGE_B(sb, t) do {                                       \
    const char* b_ = gB + (t) * 64;                               \
    llds16(b_,           ldst + (sb));                            \
    llds16(b_ + 64 * RS, ldst + (sb) + 4096);                     \
  } while (0)

  // prologue: A(0), B(0), B(1) issued; A(0)+B(0) landed at vmcnt(2)
  STAGE_A(0, 0);
  STAGE_B(16384, 0);
  STAGE_B(16384 + 8192, 1);
  asm volatile("s_waitcnt vmcnt(2)" ::: "memory");
  BAR;

  f32x16 acc[2][2] = {};

  for (int t = 0; t < NT; ++t) {
    const char* bA = lds + (t & 1) * 8192;
    const char* bB = lds + 16384 + (t % 3) * 8192;

    i32x8 av[2], bv[2];
#pragma unroll
    for (int mi = 0; mi < 2; ++mi) {
      i32x4 lo = *(const i32x4*)(bA + offA[mi][0]);
      i32x4 hi = *(const i32x4*)(bA + offA[mi][1]);
      av[mi] = __builtin_shufflevector(lo, hi, 0, 1, 2, 3, 4, 5, 6, 7);
    }
#pragma unroll
    for (int ni = 0; ni < 2; ++ni) {
      i32x4 lo = *(const i32x4*)(bB + offB[ni][0]);
      i32x4 hi = *(const i32x4*)(bB + offB[ni][1]);
      bv[ni] = __builtin_shufflevector(lo, hi, 0, 1, 2, 3, 4, 5, 6, 7);
    }

    if (t + 1 < NT) STAGE_A(((t + 1) & 1) * 8192, t + 1);
    if (t + 2 < NT) STAGE_B(16384 + ((t + 2) % 3) * 8192, t + 2);

    __builtin_amdgcn_s_setprio(1);
#pragma unroll
    for (int mi = 0; mi < 2; ++mi)
#pragma unroll
      for (int ni = 0; ni < 2; ++ni)
        acc[mi][ni] = __builtin_amdgcn_mfma_scale_f32_32x32x64_f8f6f4(
            av[mi], bv[ni], acc[mi][ni], 0, 0, 0, SC1, 0, SC1);
    __builtin_amdgcn_s_setprio(0);

    if (t + 2 < NT)      { asm volatile("s_waitcnt vmcnt(2)" ::: "memory"); BAR; }
    else if (t + 1 < NT) { asm volatile("s_waitcnt vmcnt(0)" ::: "memory"); BAR; }
  }
#undef STAGE_A
#undef STAGE_B

  // ---- epilogue: D 32x32 layout: col = rr, row = (j&3)+8*(j>>2)+4*h ------
  const int rowb = brow + wm * 64;
  const int colb = bcol + wn * 64;
#pragma unroll
  for (int mi = 0; mi < 2; ++mi) {
#pragma unroll
    for (int j = 0; j < 16; ++j) {
      const int grow = rowb + mi * 32 + (j & 3) + 8 * (j >> 2) + 4 * h;
      float v = 0.f;
#pragma unroll
      for (int ni = 0; ni < 2; ++ni) {
        const int gcol = colb + ni * 32 + rr;
        const float a = acc[mi][ni][j];
        if ((unsigned)(gcol - grow * 13) < 13u) alignedD[gcol] = a;  // raw dot
        v += ((gcol & 2047) == grow) ? 0.f : __expf(RTEMP * a);     // masked sum
      }
      v += __shfl_xor(v, 1); v += __shfl_xor(v, 2);
      v += __shfl_xor(v, 4); v += __shfl_xor(v, 8); v += __shfl_xor(v, 16);
      if (rr == 0) atomicAdd(&S_all[grow], v);    // lanes 0 (h=0) and 32 (h=1)
    }
  }
}

// ---------------------------------------------------------------------------
// Kernel 3: per row i: loss_i = sum_l [ log(exp(20 d_l) + s_i) - 20 d_l ].
// ---------------------------------------------------------------------------
__global__ __launch_bounds__(256) void k_finalize(
    const float* __restrict__ S_all, const float* __restrict__ alignedD,
    float* __restrict__ out)
{
  const int i = blockIdx.x * 256 + threadIdx.x;
  const int lane = threadIdx.x & 63, wid = threadIdx.x >> 6;
  const float s = S_all[i];
  float accv = 0.f;
#pragma unroll
  for (int l = 0; l < L_; l++) {
    const float d = RTEMP * alignedD[i * L_ + l];
    accv += logf(__expf(d) + s) - d;
  }
#pragma unroll
  for (int m = 1; m < 64; m <<= 1) accv += __shfl_xor(accv, m);
  __shared__ float wsum[4];
  if (lane == 0) wsum[wid] = accv;
  __syncthreads();
  if (threadIdx.x == 0)
    atomicAdd(out, (wsum[0] + wsum[1] + wsum[2] + wsum[3]) * (1.0f / (float)(B_ * L_)));
}

// ---------------------------------------------------------------------------
extern "C" void kernel_launch(void* const* d_in, const int* in_sizes, int n_in,
                              void* d_out, int out_size, void* d_ws, size_t ws_size,
                              hipStream_t stream) {
  const float* cls    = (const float*)d_in[0];
  const float* hidden = (const float*)d_in[1];
  float* out = (float*)d_out;

  // ws: hn8 (20,447,232) | cn8 (1,572,864) | S_all (8,192) | alignedD (106,496)
  char* ws = (char*)d_ws;
  unsigned char* hn8 = (unsigned char*)ws;
  unsigned char* cn8 = (unsigned char*)(ws + (size_t)NROW * RS);
  float* S_all    = (float*)(ws + (size_t)NROW * RS + (size_t)B_ * RS);
  float* alignedD = (float*)(ws + (size_t)NROW * RS + (size_t)B_ * RS + B_ * sizeof(float));

  k_normalize<<<(B_ + NROW) / 4, 256, 0, stream>>>(cls, hidden, cn8, hn8, S_all, out);
  k_gemm<<<NTILE, 256, 0, stream>>>(cn8, hn8, S_all, alignedD);
  k_finalize<<<B_ / 256, 256, 0, stream>>>(S_all, alignedD, out);
}

// Round 19
// 92.054 us; speedup vs baseline: 3.8830x; 2.6770x over previous
//
#include <hip/hip_runtime.h>
#include <cstdint>
#include <cstddef>

#define B_    2048
#define L_    13
#define H_    768
#define NROW  (B_ * L_)          // 26624 flattened hidden rows
#define RTEMP 20.0f              // 1 / 0.05
#define NT    12                 // K tiles: 768 / 64
#define RS    768                // fp8 row stride bytes
#define NTILE 3328               // 16 M-panels x 208 N-panels (128x128 tiles)

typedef float f32x4 __attribute__((ext_vector_type(4)));
typedef long  i64x2 __attribute__((ext_vector_type(2)));

// ---- f32 -> OCP e4m3fn, RNE, saturating (no NaN/Inf inputs here) ----------
static __device__ __forceinline__ unsigned int f2e4m3(float f) {
  unsigned int u = __float_as_uint(f);
  unsigned int s = (u >> 24) & 0x80u;
  unsigned int ua = u & 0x7fffffffu;
  if (ua >= 0x43e80000u) return s | 0x7eu;          // >= 464 -> saturate 448
  if (ua < 0x3c800000u) {                           // < 2^-6: subnormal range
    int m = (int)rintf(__uint_as_float(ua) * 512.0f);   // 0..8 (8 -> 0x08 = 2^-6)
    return s | (unsigned int)m;
  }
  unsigned int lsb = (ua >> 20) & 1u;
  unsigned int r = ua + 0x7ffffu + lsb;             // RNE to 3 mantissa bits
  int Ee = (int)((r >> 23) & 0xffu) - 127;          // carry handled naturally
  unsigned int mant = (r >> 20) & 7u;
  return s | (unsigned int)(((Ee + 7) << 3) | mant);
}

__device__ __forceinline__ void llds16(const void* g, void* l) {
  __builtin_amdgcn_global_load_lds(
      (const __attribute__((address_space(1))) void*)g,
      (__attribute__((address_space(3))) void*)l, 16, 0, 0);
}

#define BAR do { asm volatile("" ::: "memory");            \
    __builtin_amdgcn_s_barrier();                          \
    asm volatile("" ::: "memory"); } while (0)

// Interleaved fp8 row layout (per 64-B K-chunk): slot q (16B) holds
// k[q*8..q*8+7] then k[32+q*8..32+q*8+7] -> a b128 LDS read yields both
// K32-halves of a 16x16x32 fragment. 4-aligned k -> byte offset:
#define OFF8(k) ((((k) >> 6) << 6) + (((((k) & 31) >> 3)) << 4) + ((((k) & 32) ? 8 : 0)) + ((k) & 7))

// ---------------------------------------------------------------------------
// Kernel 1: L2-normalize rows (f32 math), quantize to e4m3, store in the
// interleaved chunk layout. One wave per row, 4 rows/block. Block 0 also
// zeroes S_all and out (replaces the two hipMemsetAsync dispatches).
// ---------------------------------------------------------------------------
__global__ __launch_bounds__(256) void k_normalize(
    const float* __restrict__ cls, const float* __restrict__ hidden,
    unsigned char* __restrict__ cn8, unsigned char* __restrict__ hn8,
    float* __restrict__ S_all, float* __restrict__ out)
{
  if (blockIdx.x == 0) {
#pragma unroll
    for (int i = 0; i < 8; ++i) S_all[threadIdx.x * 8 + i] = 0.0f;
    if (threadIdx.x == 0) *out = 0.0f;
  }

  const int wid = threadIdx.x >> 6, lane = threadIdx.x & 63;
  const int row = blockIdx.x * 4 + wid;
  const float4* src; unsigned char* dst;
  if (row < B_) { src = (const float4*)(cls + (size_t)row * H_);           dst = cn8 + (size_t)row * RS; }
  else          { src = (const float4*)(hidden + (size_t)(row - B_) * H_); dst = hn8 + (size_t)(row - B_) * RS; }

  float4 x0 = src[lane], x1 = src[lane + 64], x2 = src[lane + 128];
  float ss = x0.x*x0.x + x0.y*x0.y + x0.z*x0.z + x0.w*x0.w
           + x1.x*x1.x + x1.y*x1.y + x1.z*x1.z + x1.w*x1.w
           + x2.x*x2.x + x2.y*x2.y + x2.z*x2.z + x2.w*x2.w;
#pragma unroll
  for (int m = 1; m < 64; m <<= 1) ss += __shfl_xor(ss, m);
  const float sc = 1.0f / fmaxf(sqrtf(ss), 1e-8f);

  const int k = lane * 4;
  unsigned int p0 = f2e4m3(x0.x*sc) | (f2e4m3(x0.y*sc) << 8) | (f2e4m3(x0.z*sc) << 16) | (f2e4m3(x0.w*sc) << 24);
  unsigned int p1 = f2e4m3(x1.x*sc) | (f2e4m3(x1.y*sc) << 8) | (f2e4m3(x1.z*sc) << 16) | (f2e4m3(x1.w*sc) << 24);
  unsigned int p2 = f2e4m3(x2.x*sc) | (f2e4m3(x2.y*sc) << 8) | (f2e4m3(x2.z*sc) << 16) | (f2e4m3(x2.w*sc) << 24);
  *(unsigned int*)(dst + OFF8(k))       = p0;
  *(unsigned int*)(dst + OFF8(k + 256)) = p1;
  *(unsigned int*)(dst + OFF8(k + 512)) = p2;
}

// ---------------------------------------------------------------------------
// Kernel 2: fp8 GEMM = R12 frozen + ASYMMETRIC PREFETCH DEPTH (best: R14).
//   A (cn, 1.5MB, L2-hot everywhere): 2-slot dbuf, stage t+1 (shallow).
//   B (hn, 3.3MB/XCD panels, the slow operand): 3-slot ring, stage t+2.
// LDS = 2x8KB (A) + 3x8KB (B) = 40960 B; 4 x 40960 = exactly 160 KiB ->
// 4 blocks/CU (16 waves/CU — R12/R13/R15 A/B proved waves/SIMD dominate).
// Per-step FIFO: issue A(t+1)[2] then B(t+2)[2]; end-of-step vmcnt(2)
// drains B(t+1)+A(t+1), leaves B(t+2) in flight. ds_reads first in each
// step. 128x128 tile, 4 waves 2x2, wave tile 64x64 (64 AGPR + 64 VGPR =
// 128-reg quantum). Decode: 3328 = 8 XCD x (26 N x 16 M), M-inner ->
// concurrent B-panel L2 sharing (FETCH 16MB). Paired-row XOR swizzle
// (0 conflicts R2-R16). Fused exp/mask/row-sum epilogue.
// ---------------------------------------------------------------------------
__global__ __launch_bounds__(256, 4) void k_gemm(
    const unsigned char* __restrict__ cn8,
    const unsigned char* __restrict__ hn8,
    float* __restrict__ S_all,
    float* __restrict__ alignedD)
{
  __shared__ __align__(16) char lds[40960];   // A: 2x8KB @0; B: 3x8KB @16384

  const int tid  = threadIdx.x;
  const int lane = tid & 63;
  const int wid  = tid >> 6;           // 0..3
  const int wm   = wid >> 1;           // 0..1  (M half: 64 rows)
  const int wn   = wid & 1;            // 0..1  (N half: 64 cols)
  const int fr   = lane & 15, q = lane >> 4, fr2 = (lane & 15) >> 1;

  // fragment read offsets (paired-row XOR swizzle, validated R2-R16)
  const int swz  = ((q | ((fr & 1) << 2)) ^ (fr2 & 7)) << 4;
  const int offA = wm * 4096 + fr2 * 128 + swz;            // + mi*1024, mi<4
  const int offB = wn * 4096 + fr2 * 128 + swz;            // + ni*1024, ni<4

  // staging map (linear LDS dest, inverse-swizzled global source)
  const int slot_un = (tid & 7) ^ ((tid >> 3) & 7);
  const int srow = 2 * (tid >> 3) + (slot_un >> 2);   // 0..63
  const int scb  = (slot_un & 3) << 4;
  char* ldst = lds + tid * 16;

  // R12 decode: 3328 = 8 XCD x (26 N x 16 M), M-inner within XCD.
  const int tile = blockIdx.x;
  const int xcd  = tile & 7;
  const int idx  = tile >> 3;
  const int brow = (idx & 15) << 7;
  const int bcol = (xcd * 26 + (idx >> 4)) << 7;

  const char* gA = (const char*)cn8 + (size_t)(brow + srow) * RS + scb;
  const char* gB = (const char*)hn8 + (size_t)(bcol + srow) * RS + scb;

  // A slot s (s<2) at s*8192: rows 0..63 at +0, 64..127 at +4096.
  // B slot s (s<3) at 16384 + s*8192: same split.
#define STAGE_A(sb, t) do {                                       \
    char* d_ = ldst + (sb);                                       \
    const char* a_ = gA + (t) * 64;                               \
    llds16(a_,           d_);                                     \
    llds16(a_ + 64 * RS, d_ + 4096);                              \
  } while (0)
#define STAGE_B(sb, t) do {                                       \
    char* d_ = ldst + (sb);                                       \
    const char* b_ = gB + (t) * 64;                               \
    llds16(b_,           d_);                                     \
    llds16(b_ + 64 * RS, d_ + 4096);                              \
  } while (0)

  // prologue: A(0), B(0), B(1) issued (6 loads); need A(0)+B(0) -> vmcnt(2)
  STAGE_A(0, 0);
  STAGE_B(16384, 0);
  STAGE_B(16384 + 8192, 1);
  asm volatile("s_waitcnt vmcnt(2)" ::: "memory");
  BAR;

  f32x4 acc[4][4] = {};

  for (int t = 0; t < NT; ++t) {
    const char* bA = lds + (t & 1) * 8192;
    const char* bB = lds + 16384 + (t % 3) * 8192;

    // ds_reads first: shortest lgkm path into the MFMA block
    i64x2 av[4], bv[4];
#pragma unroll
    for (int i = 0; i < 4; ++i) av[i] = *(const i64x2*)(bA + offA + i * 1024);
#pragma unroll
    for (int i = 0; i < 4; ++i) bv[i] = *(const i64x2*)(bB + offB + i * 1024);

    if (t + 1 < NT) STAGE_A(((t + 1) & 1) * 8192, t + 1);
    if (t + 2 < NT) STAGE_B(16384 + ((t + 2) % 3) * 8192, t + 2);

    __builtin_amdgcn_s_setprio(1);
#pragma unroll
    for (int mi = 0; mi < 4; ++mi)
#pragma unroll
      for (int ni = 0; ni < 4; ++ni)
        acc[mi][ni] = __builtin_amdgcn_mfma_f32_16x16x32_fp8_fp8(
            av[mi][0], bv[ni][0], acc[mi][ni], 0, 0, 0);
#pragma unroll
    for (int mi = 0; mi < 4; ++mi)
#pragma unroll
      for (int ni = 0; ni < 4; ++ni)
        acc[mi][ni] = __builtin_amdgcn_mfma_f32_16x16x32_fp8_fp8(
            av[mi][1], bv[ni][1], acc[mi][ni], 0, 0, 0);
    __builtin_amdgcn_s_setprio(0);

    // counted drain: B(t+1)+A(t+1) landed; B(t+2)'s 2 stay in flight.
    if (t + 2 < NT)      { asm volatile("s_waitcnt vmcnt(2)" ::: "memory"); BAR; }
    else if (t + 1 < NT) { asm volatile("s_waitcnt vmcnt(0)" ::: "memory"); BAR; }
    // t == NT-1: nothing outstanding, no further LDS writes -> no barrier
  }
#undef STAGE_A
#undef STAGE_B

  // epilogue: row = brow+wm*64+mi*16+q*4+j, col = bcol+wn*64+ni*16+fr
  const int rowb = brow + wm * 64;
  const int colb = bcol + wn * 64;
#pragma unroll
  for (int mi = 0; mi < 4; ++mi) {
#pragma unroll
    for (int j = 0; j < 4; ++j) {
      const int grow = rowb + mi * 16 + q * 4 + j;
      float v = 0.f;
#pragma unroll
      for (int ni = 0; ni < 4; ++ni) {
        const int gcol = colb + ni * 16 + fr;
        const float a = acc[mi][ni][j];
        if ((unsigned)(gcol - grow * 13) < 13u) alignedD[gcol] = a;  // raw dot
        v += ((gcol & 2047) == grow) ? 0.f : __expf(RTEMP * a);     // masked sum
      }
      v += __shfl_xor(v, 1); v += __shfl_xor(v, 2);
      v += __shfl_xor(v, 4); v += __shfl_xor(v, 8);
      if (fr == 0) atomicAdd(&S_all[grow], v);
    }
  }
}

// ---------------------------------------------------------------------------
// Kernel 3: per row i: loss_i = sum_l [ log(exp(20 d_l) + s_i) - 20 d_l ].
// ---------------------------------------------------------------------------
__global__ __launch_bounds__(256) void k_finalize(
    const float* __restrict__ S_all, const float* __restrict__ alignedD,
    float* __restrict__ out)
{
  const int i = blockIdx.x * 256 + threadIdx.x;
  const int lane = threadIdx.x & 63, wid = threadIdx.x >> 6;
  const float s = S_all[i];
  float accv = 0.f;
#pragma unroll
  for (int l = 0; l < L_; l++) {
    const float d = RTEMP * alignedD[i * L_ + l];
    accv += logf(__expf(d) + s) - d;
  }
#pragma unroll
  for (int m = 1; m < 64; m <<= 1) accv += __shfl_xor(accv, m);
  __shared__ float wsum[4];
  if (lane == 0) wsum[wid] = accv;
  __syncthreads();
  if (threadIdx.x == 0)
    atomicAdd(out, (wsum[0] + wsum[1] + wsum[2] + wsum[3]) * (1.0f / (float)(B_ * L_)));
}

// ---------------------------------------------------------------------------
extern "C" void kernel_launch(void* const* d_in, const int* in_sizes, int n_in,
                              void* d_out, int out_size, void* d_ws, size_t ws_size,
                              hipStream_t stream) {
  const float* cls    = (const float*)d_in[0];
  const float* hidden = (const float*)d_in[1];
  float* out = (float*)d_out;

  // ws: hn8 (20,447,232) | cn8 (1,572,864) | S_all (8,192) | alignedD (106,496)
  char* ws = (char*)d_ws;
  unsigned char* hn8 = (unsigned char*)ws;
  unsigned char* cn8 = (unsigned char*)(ws + (size_t)NROW * RS);
  float* S_all    = (float*)(ws + (size_t)NROW * RS + (size_t)B_ * RS);
  float* alignedD = (float*)(ws + (size_t)NROW * RS + (size_t)B_ * RS + B_ * sizeof(float));

  k_normalize<<<(B_ + NROW) / 4, 256, 0, stream>>>(cls, hidden, cn8, hn8, S_all, out);
  k_gemm<<<NTILE, 256, 0, stream>>>(cn8, hn8, S_all, alignedD);
  k_finalize<<<B_ / 256, 256, 0, stream>>>(S_all, alignedD, out);
}